// Round 6
// baseline (1718.723 us; speedup 1.0000x reference)
//
#include <hip/hip_runtime.h>
#include <hip/hip_bf16.h>
#include <math.h>

namespace {

constexpr int cE  = 512;    // embed dim
constexpr int cH  = 512;    // total hidden (2 dirs)
constexpr int cT  = 76;     // tags
constexpr int cB  = 256;    // batch
constexpr int cS  = 128;    // seq len
constexpr int cHD = 256;    // per-dir hidden
constexpr int cNG = 1024;   // 4*HD gate width
constexpr int cM  = cS * cB; // 32768 rows of (S,B) flattened
constexpr int cV  = 30000;  // vocab
constexpr int cBH = cB * cHD; // 65536

typedef __attribute__((ext_vector_type(8))) short bf16x8;
typedef __attribute__((ext_vector_type(4))) float f32x4;
typedef unsigned long long ull_t;

typedef const __attribute__((address_space(1))) unsigned int* gas_ptr;
typedef __attribute__((address_space(3))) unsigned int* las_ptr;

__device__ __forceinline__ float fsig(float x) { return 1.0f / (1.0f + __expf(-x)); }
__device__ __forceinline__ float ftanh_(float x) {
  float e = __expf(2.0f * fabsf(x));
  float t = 1.0f - 2.0f / (e + 1.0f);
  return copysignf(t, x);
}
__device__ __forceinline__ unsigned short f2bf(float f) {
  __hip_bfloat16 h = __float2bfloat16(f);
  return *reinterpret_cast<unsigned short*>(&h);
}
__device__ __forceinline__ float bf2f(unsigned short u) {
  unsigned int v = ((unsigned int)u) << 16;
  return *reinterpret_cast<float*>(&v);
}
__device__ __forceinline__ void gload_lds16(const void* g, void* l) {
  __builtin_amdgcn_global_load_lds((gas_ptr)g, (las_ptr)l, 16, 0, 0);
}

// ---------------------------------------------------------------------------
// Prep: bf16-convert embed table, W_ih(2), W_hh(2), h0; W_out zero-padded to
// 128 rows. Vectorized float4 -> ushort4 grid-stride.
// ---------------------------------------------------------------------------
__global__ __launch_bounds__(256) void k_prep(
    const float* __restrict__ embed,
    const float* __restrict__ Wihf, const float* __restrict__ Wihb,
    const float* __restrict__ Whhf, const float* __restrict__ Whhb,
    const float* __restrict__ h0,   const float* __restrict__ Wout,
    unsigned short* __restrict__ tbl, unsigned short* __restrict__ wih,
    unsigned short* __restrict__ whh, unsigned short* __restrict__ hInit,
    unsigned short* __restrict__ WoutP)
{
  const int gid = blockIdx.x * 256 + threadIdx.x;
  constexpr int NT  = cV * cE / 4;        // 3,840,000
  constexpr int NI  = cNG * cE / 4;       // 131,072
  constexpr int NH  = cNG * cHD / 4;      // 65,536
  constexpr int NH0 = 2 * cBH / 4;        // 32,768
  constexpr int NW  = 128 * cE / 4;       // 16,384 (padded W_out)
  constexpr int total = NT + 2*NI + 2*NH + NH0 + NW;
  for (int q = gid; q < total; q += 4096 * 256) {
    const float* src; unsigned short* dst; int lq;
    bool zero = false;
    if (q < NT)               { src = embed; dst = tbl;              lq = q; }
    else if (q < NT+NI)       { src = Wihf;  dst = wih;              lq = q-NT; }
    else if (q < NT+2*NI)     { src = Wihb;  dst = wih + cNG*cE;     lq = q-NT-NI; }
    else if (q < NT+2*NI+NH)  { src = Whhf;  dst = whh;              lq = q-NT-2*NI; }
    else if (q < NT+2*NI+2*NH){ src = Whhb;  dst = whh + cNG*cHD;    lq = q-NT-2*NI-NH; }
    else if (q < NT+2*NI+2*NH+NH0){ src = h0; dst = hInit;           lq = q-NT-2*NI-2*NH; }
    else { lq = q-NT-2*NI-2*NH-NH0; src = Wout; dst = WoutP; zero = (lq >= cT*cE/4); }
    float4 v = make_float4(0.f,0.f,0.f,0.f);
    if (!zero) v = *(const float4*)(src + (size_t)lq * 4);
    ushort4 u;
    u.x = f2bf(v.x); u.y = f2bf(v.y); u.z = f2bf(v.z); u.w = f2bf(v.w);
    *(ushort4*)(dst + (size_t)lq * 4) = u;
  }
}

// ---------------------------------------------------------------------------
// Embed projection (unchanged R4): bf16 MFMA + global_load_lds staging,
// XCD-aware 1D remap. P[m][n] = sum_k tbl[ids(m)][k]*Wih[n][k] + b1[n]+b2[n]
// ---------------------------------------------------------------------------
__global__ __launch_bounds__(256) void k_embed_mfma(
    const int* __restrict__ ids,
    const unsigned short* __restrict__ tbl,
    const unsigned short* __restrict__ Wih,
    const float* __restrict__ b1f, const float* __restrict__ b2f,
    const float* __restrict__ b1b, const float* __restrict__ b2b,
    __hip_bfloat16* __restrict__ Pf, __hip_bfloat16* __restrict__ Pb)
{
  const int bid = blockIdx.x;
  const int xcd = bid & 7;
  const int jj  = bid >> 3;
  const int m_tile = xcd * 32 + (jj >> 4);
  const int nz  = jj & 15;
  const int n_tile = nz & 7;
  const int d   = nz >> 3;

  const unsigned short* W = Wih + (size_t)d * cNG * cE;
  const float* b1 = d ? b1b : b1f;
  const float* b2 = d ? b2b : b2f;
  unsigned short* P = (unsigned short*)(d ? Pb : Pf);

  const int n0 = n_tile * 128;
  const int m0 = m_tile * 128;
  const int tid = threadIdx.x;

  __shared__ unsigned short Al[128 * 64];
  __shared__ unsigned short Bl[128 * 64];
  __shared__ float bias_s[128];
  if (tid < 128) bias_s[tid] = b1[n0 + tid] + b2[n0 + tid];

  const int lane = tid & 63, wave = tid >> 6;
  const int wm = wave >> 1, wn = wave & 1;
  const int fr = lane & 15, fq = lane >> 4;

  const int srow = wave * 32;
  const int lrow = lane >> 3;
  const int lch  = lane & 7;
  int aid[4];
#pragma unroll
  for (int q = 0; q < 4; ++q) {
    const int m = m0 + srow + q * 8 + lrow;
    aid[q] = ids[(m & (cB - 1)) * cS + (m >> 8)];
  }

  f32x4 acc[4][4];
#pragma unroll
  for (int i = 0; i < 4; ++i)
#pragma unroll
    for (int j = 0; j < 4; ++j) acc[i][j] = (f32x4){0.f, 0.f, 0.f, 0.f};

  for (int kt = 0; kt < cE / 64; ++kt) {
    __syncthreads();
#pragma unroll
    for (int q = 0; q < 4; ++q) {
      const unsigned short* ga = tbl + (size_t)aid[q] * cE + kt * 64 + lch * 8;
      const unsigned short* gb = W + (size_t)(n0 + srow + q * 8 + lrow) * cE + kt * 64 + lch * 8;
      gload_lds16(ga, Al + (srow + q * 8) * 64);
      gload_lds16(gb, Bl + (srow + q * 8) * 64);
    }
    __syncthreads();
#pragma unroll
    for (int ks = 0; ks < 2; ++ks) {
      bf16x8 aF[4], bF[4];
#pragma unroll
      for (int i = 0; i < 4; ++i)
        aF[i] = *(const bf16x8*)(Al + (wm * 64 + i * 16 + fr) * 64 + ks * 32 + fq * 8);
#pragma unroll
      for (int j = 0; j < 4; ++j)
        bF[j] = *(const bf16x8*)(Bl + (wn * 64 + j * 16 + fr) * 64 + ks * 32 + fq * 8);
#pragma unroll
      for (int i = 0; i < 4; ++i)
#pragma unroll
        for (int j = 0; j < 4; ++j)
          acc[i][j] = __builtin_amdgcn_mfma_f32_16x16x32_bf16(aF[i], bF[j], acc[i][j], 0, 0, 0);
    }
  }

#pragma unroll
  for (int i = 0; i < 4; ++i)
#pragma unroll
    for (int j = 0; j < 4; ++j) {
      const int gcol = wn * 64 + j * 16 + fr;
#pragma unroll
      for (int r = 0; r < 4; ++r) {
        const int grow = m0 + wm * 64 + i * 16 + fq * 4 + r;
        P[(size_t)grow * cNG + n0 + gcol] = f2bf(acc[i][j][r] + bias_s[gcol]);
      }
    }
}

// ---------------------------------------------------------------------------
// LSTM recurrence v3: ONE workgroup per (dir, 16-batch-tile) = 32 blocks of
// 1024 threads (16 waves). h-exchange entirely in LDS (ping-pong A buffer,
// one __syncthreads per step) — no global atomics, no cross-block coherence.
// Wave w owns j-tile [16w,16w+16) x 4 gates: W_hh in 128 VGPRs. M=16, K=256.
// P prefetched one step ahead into registers. h also streamed to hHist (bf16)
// for the emissions GEMM. LDS row stride 264 shorts: 8 bank-start groups.
// ---------------------------------------------------------------------------
__global__ __launch_bounds__(1024, 4) void k_lstm_block(
    const unsigned short* __restrict__ Wbf,   // [2][1024][256] bf16
    const unsigned short* __restrict__ Pf_,
    const unsigned short* __restrict__ Pb_,
    const float* __restrict__ c0,             // [2][256][256] f32
    const unsigned short* __restrict__ hInit, // [2][256][256] bf16
    unsigned short* __restrict__ hHist)       // [S][2][256][256] bf16
{
  const int bid = blockIdx.x;
  const int d   = bid & 1;
  const int b0  = (bid >> 1) * 16;
  const int tid = threadIdx.x;
  const int lane = tid & 63, w = tid >> 6;     // wave 0..15
  const int fr = lane & 15, fq = lane >> 4;
  const int j0 = w * 16;
  const int jj = j0 + fr;

  const unsigned short* P = d ? Pb_ : Pf_;
  const unsigned short* wbase = Wbf + (size_t)d * cNG * cHD;

  constexpr int RS = 264;                      // LDS row stride (shorts)
  __shared__ unsigned short Abuf[2][16 * RS];  // ping-pong h (A operand)

  // ---- W_hh fragments resident in registers: wreg[k0][gate] (128 VGPR)
  bf16x8 wreg[8][4];
#pragma unroll
  for (int k0 = 0; k0 < 8; ++k0)
#pragma unroll
    for (int gg = 0; gg < 4; ++gg)
      wreg[k0][gg] = *(const bf16x8*)(wbase + (size_t)(gg * cHD + j0 + fr) * cHD + k0 * 32 + fq * 8);

  // ---- c resident in registers (4 b-rows x 1 j per lane)
  float creg[4];
#pragma unroll
  for (int r = 0; r < 4; ++r)
    creg[r] = c0[d * cBH + (b0 + fq * 4 + r) * cHD + jj];

  // ---- stage h0 slice into Abuf[0]
  {
    const int row = tid >> 6;          // 0..15
    const int c4  = (tid & 63) * 4;    // 0..252
    const ushort4 v = *(const ushort4*)(hInit + (size_t)d * cBH + (b0 + row) * cHD + c4);
    *(ushort4*)(&Abuf[0][row * RS + c4]) = v;
  }

  // ---- P prefetch for step 0
  unsigned short pv[4][4], pvn[4][4];
  {
    const unsigned short* Pt = P + (size_t)(d ? cS - 1 : 0) * cB * cNG;
#pragma unroll
    for (int gg = 0; gg < 4; ++gg)
#pragma unroll
      for (int r = 0; r < 4; ++r)
        pv[gg][r] = Pt[(size_t)(b0 + fq * 4 + r) * cNG + gg * cHD + jj];
  }
  __syncthreads();

  for (int t = 0; t < cS; ++t) {
    const int te = d ? (cS - 1 - t) : t;
    const unsigned short* cur = Abuf[t & 1];
    unsigned short* nxt = Abuf[(t + 1) & 1];

    // ---- A-fragments from LDS (M=16: row=fr, k=k0*32+fq*8)
    bf16x8 aF[8];
#pragma unroll
    for (int k0 = 0; k0 < 8; ++k0)
      aF[k0] = *(const bf16x8*)(cur + fr * RS + k0 * 32 + fq * 8);

    // ---- MFMA: M=16, N=16 x 4 gates, K=256
    f32x4 acc[4];
#pragma unroll
    for (int gg = 0; gg < 4; ++gg) acc[gg] = (f32x4){0.f, 0.f, 0.f, 0.f};
#pragma unroll
    for (int k0 = 0; k0 < 8; ++k0)
#pragma unroll
      for (int gg = 0; gg < 4; ++gg)
        acc[gg] = __builtin_amdgcn_mfma_f32_16x16x32_bf16(aF[k0], wreg[k0][gg], acc[gg], 0, 0, 0);

    // ---- prefetch P for step t+1 (latency hides under epilogue+barrier)
    if (t != cS - 1) {
      const int tn = d ? (te - 1) : (te + 1);
      const unsigned short* Pt = P + (size_t)tn * cB * cNG;
#pragma unroll
      for (int gg = 0; gg < 4; ++gg)
#pragma unroll
        for (int r = 0; r < 4; ++r)
          pvn[gg][r] = Pt[(size_t)(b0 + fq * 4 + r) * cNG + gg * cHD + jj];
    }

    // ---- gates -> c,h ; h into next A buffer + global hHist
#pragma unroll
    for (int r = 0; r < 4; ++r) {
      const int row = fq * 4 + r;                      // local b-row 0..15
      const float zi = acc[0][r] + bf2f(pv[0][r]);
      const float zf = acc[1][r] + bf2f(pv[1][r]);
      const float zg = acc[2][r] + bf2f(pv[2][r]);
      const float zo = acc[3][r] + bf2f(pv[3][r]);
      const float cc = fsig(zf) * creg[r] + fsig(zi) * ftanh_(zg);
      creg[r] = cc;
      const unsigned short h = f2bf(fsig(zo) * ftanh_(cc));
      nxt[row * RS + jj] = h;
      hHist[(((size_t)te * 2 + d) * cB + b0 + row) * cHD + jj] = h;
    }

#pragma unroll
    for (int gg = 0; gg < 4; ++gg)
#pragma unroll
      for (int r = 0; r < 4; ++r) pv[gg][r] = pvn[gg][r];

    __syncthreads();   // h(nxt) visible to all waves; cur free to overwrite
  }
}

// ---------------------------------------------------------------------------
// Emissions: bf16 MFMA. em[m][n] = sum_k hfeat[m][k]*WoutP[n][k] + b_out[n]
// A = hHist ([t][d][b][j] -> row m=t*256+b, k=d*256+j). N padded to 128.
// ---------------------------------------------------------------------------
__global__ __launch_bounds__(256) void k_em_mfma(
    const unsigned short* __restrict__ hHist,  // [S][2][256][256] bf16
    const unsigned short* __restrict__ WoutP,  // [128][512] bf16 (rows>=76 = 0)
    const float* __restrict__ b_out, float* __restrict__ em)
{
  const int m0 = blockIdx.x * 128;
  const int tid = threadIdx.x;

  __shared__ unsigned short Al[128 * 64];
  __shared__ unsigned short Bl[128 * 64];
  __shared__ float bias_s[128];
  if (tid < 128) bias_s[tid] = (tid < cT) ? b_out[tid] : 0.f;

  const int lane = tid & 63, wave = tid >> 6;
  const int wm = wave >> 1, wn = wave & 1;
  const int fr = lane & 15, fq = lane >> 4;
  const int srow = wave * 32;
  const int lrow = lane >> 3;
  const int lch  = lane & 7;

  f32x4 acc[4][4];
#pragma unroll
  for (int i = 0; i < 4; ++i)
#pragma unroll
    for (int j = 0; j < 4; ++j) acc[i][j] = (f32x4){0.f, 0.f, 0.f, 0.f};

  for (int kt = 0; kt < 8; ++kt) {
    const int d  = kt >> 2;
    const int ko = (kt & 3) * 64;
    __syncthreads();
#pragma unroll
    for (int q = 0; q < 4; ++q) {
      const int row = srow + q * 8 + lrow;
      const int m = m0 + row;
      const int t = m >> 8, b = m & 255;
      const unsigned short* ga = hHist + (((size_t)t * 2 + d) * cB + b) * cHD + ko + lch * 8;
      const unsigned short* gb = WoutP + (size_t)row * cH + kt * 64 + lch * 8;
      gload_lds16(ga, Al + (srow + q * 8) * 64);
      gload_lds16(gb, Bl + (srow + q * 8) * 64);
    }
    __syncthreads();
#pragma unroll
    for (int ks = 0; ks < 2; ++ks) {
      bf16x8 aF[4], bF[4];
#pragma unroll
      for (int i = 0; i < 4; ++i)
        aF[i] = *(const bf16x8*)(Al + (wm * 64 + i * 16 + fr) * 64 + ks * 32 + fq * 8);
#pragma unroll
      for (int j = 0; j < 4; ++j)
        bF[j] = *(const bf16x8*)(Bl + (wn * 64 + j * 16 + fr) * 64 + ks * 32 + fq * 8);
#pragma unroll
      for (int i = 0; i < 4; ++i)
#pragma unroll
        for (int j = 0; j < 4; ++j)
          acc[i][j] = __builtin_amdgcn_mfma_f32_16x16x32_bf16(aF[i], bF[j], acc[i][j], 0, 0, 0);
    }
  }

#pragma unroll
  for (int i = 0; i < 4; ++i)
#pragma unroll
    for (int j = 0; j < 4; ++j) {
      const int gcol = wn * 64 + j * 16 + fr;
      if (gcol < cT) {
#pragma unroll
        for (int r = 0; r < 4; ++r) {
          const int grow = m0 + wm * 64 + i * 16 + fq * 4 + r;
          em[(size_t)grow * cT + gcol] = acc[i][j][r] + bias_s[gcol];
        }
      }
    }
}

// ---------------------------------------------------------------------------
// CRF: one block per batch element, 320 threads (5 waves). (unchanged R2)
// ---------------------------------------------------------------------------
__global__ __launch_bounds__(320) void k_crf(
    const float* __restrict__ em,
    const int* __restrict__ tag_ids,
    const int* __restrict__ lengths,
    const float* __restrict__ start_trans,
    const float* __restrict__ end_trans,
    const float* __restrict__ trans,
    float* __restrict__ llh)
{
  const int b = blockIdx.x;
  const int tid = threadIdx.x;
  const int len = lengths[b];

  __shared__ float trans_t[80 * 81];
  __shared__ float em_s[cS * 80];
  __shared__ float a0[80], a1[80];
  __shared__ float red[128];
  __shared__ float score_sh;

  for (int idx = tid; idx < cT * cT; idx += 320) {
    const int i = idx / cT, jt = idx - i * cT;
    trans_t[jt * 81 + i] = trans[idx];
  }
  for (int idx = tid; idx < cS * cT; idx += 320) {
    const int t = idx / cT, jt = idx - t * cT;
    em_s[t * 80 + jt] = em[((size_t)t * cB + b) * cT + jt];
  }
  __syncthreads();

  float contrib = 0.f;
  if (tid < cS) {
    const int t = tid;
    if (t == 0) {
      const int tg = tag_ids[b * cS];
      contrib = start_trans[tg] + em_s[tg];
    } else if (t < len) {
      const int tg = tag_ids[b * cS + t];
      const int tp = tag_ids[b * cS + t - 1];
      contrib = trans_t[tg * 81 + tp] + em_s[t * 80 + tg];
    }
    if (t == len - 1) contrib += end_trans[tag_ids[b * cS + len - 1]];
  }
  if (tid < 128) red[tid] = contrib;
  __syncthreads();
  for (int s = 64; s > 0; s >>= 1) {
    if (tid < s) red[tid] += red[tid + s];
    __syncthreads();
  }
  if (tid == 0) score_sh = red[0];

  const int j   = tid >> 2;
  const int sub = tid & 3;
  const int i0  = sub * 19;
  float* cur = a0;
  float* nxt = a1;
  if (sub == 0 && j < cT) cur[j] = start_trans[j] + em_s[j];
  __syncthreads();
  for (int t = 1; t < len; ++t) {
    const float mref = cur[0];
    const float* trow = &trans_t[j * 81 + i0];
    const float* crow = &cur[i0];
    float s = 0.f;
#pragma unroll
    for (int q = 0; q < 19; ++q)
      s += __expf(crow[q] + trow[q] - mref);
    s += __shfl_xor(s, 1);
    s += __shfl_xor(s, 2);
    if (sub == 0 && j < cT) nxt[j] = mref + __logf(s) + em_s[t * 80 + j];
    __syncthreads();
    float* tp2 = cur; cur = nxt; nxt = tp2;
  }

  const float v = (tid < cT) ? cur[tid] + end_trans[tid] : -1e30f;
  if (tid < 128) red[tid] = v;
  __syncthreads();
  for (int s = 64; s > 0; s >>= 1) {
    if (tid < s) red[tid] = fmaxf(red[tid], red[tid + s]);
    __syncthreads();
  }
  const float mx = red[0];
  __syncthreads();
  if (tid < 128) red[tid] = (tid < cT) ? __expf(v - mx) : 0.f;
  __syncthreads();
  for (int s = 64; s > 0; s >>= 1) {
    if (tid < s) red[tid] += red[tid + s];
    __syncthreads();
  }
  if (tid == 0) llh[b] = score_sh - (mx + __logf(red[0]));
}

__global__ __launch_bounds__(256) void k_final(const float* __restrict__ llh,
                                               float* __restrict__ out)
{
  __shared__ float red[256];
  const int tid = threadIdx.x;
  red[tid] = llh[tid];
  __syncthreads();
  for (int s = 128; s > 0; s >>= 1) {
    if (tid < s) red[tid] += red[tid + s];
    __syncthreads();
  }
  if (tid == 0) out[0] = -red[0] * (1.0f / cB);
}

} // anonymous namespace

extern "C" void kernel_launch(void* const* d_in, const int* in_sizes, int n_in,
                              void* d_out, int out_size, void* d_ws, size_t ws_size,
                              hipStream_t stream) {
  const int*   input_ids   = (const int*)  d_in[0];
  const int*   tag_ids     = (const int*)  d_in[1];
  const int*   lengths     = (const int*)  d_in[2];
  const float* embed_table = (const float*)d_in[3];
  const float* W_ih_f      = (const float*)d_in[4];
  const float* W_hh_f      = (const float*)d_in[5];
  const float* b_ih_f      = (const float*)d_in[6];
  const float* b_hh_f      = (const float*)d_in[7];
  const float* W_ih_b      = (const float*)d_in[8];
  const float* W_hh_b      = (const float*)d_in[9];
  const float* b_ih_b      = (const float*)d_in[10];
  const float* b_hh_b      = (const float*)d_in[11];
  const float* W_out       = (const float*)d_in[12];
  const float* b_out       = (const float*)d_in[13];
  const float* start_trans = (const float*)d_in[14];
  const float* end_trans   = (const float*)d_in[15];
  const float* trans       = (const float*)d_in[16];
  const float* h0          = (const float*)d_in[17];
  const float* c0          = (const float*)d_in[18];
  float* out = (float*)d_out;

  // workspace layout (lifetime-aliased; ~180 MiB total):
  //  [0,64M) Pf   [64M,128M) Pb
  //  [128M,+30.72M) tbl (embed-only) / hHist [128M,+32M) (lstm+em; tbl dead)
  //  [160M,+4M) wih (embed-only)
  //  [165M,+9.96M) em f32 (post-lstm)
  //  [176M...) whh, hInit, WoutP, llh
  char* wsb = (char*)d_ws;
  const size_t MB = 1024 * 1024;
  __hip_bfloat16* Pf = (__hip_bfloat16*)(wsb);
  __hip_bfloat16* Pb = (__hip_bfloat16*)(wsb + 64 * MB);
  unsigned short* tbl   = (unsigned short*)(wsb + 128 * MB);
  unsigned short* hHist = (unsigned short*)(wsb + 128 * MB);   // aliases tbl
  unsigned short* wih   = (unsigned short*)(wsb + 160 * MB);
  float*          em    = (float*)         (wsb + 165 * MB);
  unsigned short* whh   = (unsigned short*)(wsb + 176 * MB);   // 1 MiB
  unsigned short* hInit = (unsigned short*)(wsb + 177 * MB);   // 256 KiB
  unsigned short* WoutP = (unsigned short*)(wsb + 178 * MB);   // 128 KiB
  float*          llh   = (float*)         (wsb + 179 * MB);

  // 0) prep: bf16 conversions + padded W_out
  k_prep<<<4096, 256, 0, stream>>>(embed_table, W_ih_f, W_ih_b, W_hh_f, W_hh_b,
                                   h0, W_out, tbl, wih, whh, hInit, WoutP);

  // 1) input projections (gather GEMM), bf16 MFMA + global_load_lds staging
  k_embed_mfma<<<4096, 256, 0, stream>>>(input_ids, tbl, wih,
                                         b_ih_f, b_hh_f, b_ih_b, b_hh_b, Pf, Pb);

  // 2) full recurrence: 32 blocks x 1024 thr, LDS-only h exchange
  k_lstm_block<<<32, 1024, 0, stream>>>(whh, (const unsigned short*)Pf,
                                        (const unsigned short*)Pb,
                                        c0, hInit, hHist);

  // 3) emissions from bf16 h-history (MFMA)
  k_em_mfma<<<cM / 128, 256, 0, stream>>>(hHist, WoutP, b_out, em);

  // 4) CRF per batch element + final mean
  k_crf<<<cB, 320, 0, stream>>>(em, tag_ids, lengths, start_trans, end_trans, trans, llh);
  k_final<<<1, 256, 0, stream>>>(llh, out);
}

// Round 8
// 1093.189 us; speedup vs baseline: 1.5722x; 1.5722x over previous
//
#include <hip/hip_runtime.h>
#include <hip/hip_bf16.h>
#include <math.h>

namespace {

constexpr int cE  = 512;    // embed dim
constexpr int cH  = 512;    // total hidden (2 dirs)
constexpr int cT  = 76;     // tags
constexpr int cB  = 256;    // batch
constexpr int cS  = 128;    // seq len
constexpr int cHD = 256;    // per-dir hidden
constexpr int cNG = 1024;   // 4*HD gate width
constexpr int cM  = cS * cB; // 32768 rows of (S,B) flattened
constexpr int cV  = 30000;  // vocab
constexpr int cBH = cB * cHD; // 65536

typedef __attribute__((ext_vector_type(8))) short bf16x8;
typedef __attribute__((ext_vector_type(4))) float f32x4;
typedef unsigned long long ull_t;

typedef const __attribute__((address_space(1))) unsigned int* gas_ptr;
typedef __attribute__((address_space(3))) unsigned int* las_ptr;

__device__ __forceinline__ float fsig(float x) { return 1.0f / (1.0f + __expf(-x)); }
__device__ __forceinline__ float ftanh_(float x) {
  float e = __expf(2.0f * fabsf(x));
  float t = 1.0f - 2.0f / (e + 1.0f);
  return copysignf(t, x);
}
__device__ __forceinline__ unsigned short f2bf(float f) {
  __hip_bfloat16 h = __float2bfloat16(f);
  return *reinterpret_cast<unsigned short*>(&h);
}
__device__ __forceinline__ float bf2f(unsigned short u) {
  unsigned int v = ((unsigned int)u) << 16;
  return *reinterpret_cast<float*>(&v);
}
__device__ __forceinline__ void gload_lds16(const void* g, void* l) {
  __builtin_amdgcn_global_load_lds((gas_ptr)g, (las_ptr)l, 16, 0, 0);
}

// ---------------------------------------------------------------------------
// Prep: bf16-convert embed table, W_ih(2), W_hh(2), h0; W_out zero-padded to
// 128 rows; zero barrier region. Vectorized float4 -> ushort4 grid-stride.
// ---------------------------------------------------------------------------
__global__ __launch_bounds__(256) void k_prep(
    const float* __restrict__ embed,
    const float* __restrict__ Wihf, const float* __restrict__ Wihb,
    const float* __restrict__ Whhf, const float* __restrict__ Whhb,
    const float* __restrict__ h0,   const float* __restrict__ Wout,
    unsigned short* __restrict__ tbl, unsigned short* __restrict__ wih,
    unsigned short* __restrict__ whh, unsigned short* __restrict__ hInit,
    unsigned short* __restrict__ WoutP, unsigned int* __restrict__ bar)
{
  const int gid = blockIdx.x * 256 + threadIdx.x;
  if (gid < 1024) bar[gid] = 0;
  constexpr int NT  = cV * cE / 4;        // 3,840,000
  constexpr int NI  = cNG * cE / 4;       // 131,072
  constexpr int NH  = cNG * cHD / 4;      // 65,536
  constexpr int NH0 = 2 * cBH / 4;        // 32,768
  constexpr int NW  = 128 * cE / 4;       // 16,384 (padded W_out)
  constexpr int total = NT + 2*NI + 2*NH + NH0 + NW;
  for (int q = gid; q < total; q += 4096 * 256) {
    const float* src; unsigned short* dst; int lq;
    bool zero = false;
    if (q < NT)               { src = embed; dst = tbl;              lq = q; }
    else if (q < NT+NI)       { src = Wihf;  dst = wih;              lq = q-NT; }
    else if (q < NT+2*NI)     { src = Wihb;  dst = wih + cNG*cE;     lq = q-NT-NI; }
    else if (q < NT+2*NI+NH)  { src = Whhf;  dst = whh;              lq = q-NT-2*NI; }
    else if (q < NT+2*NI+2*NH){ src = Whhb;  dst = whh + cNG*cHD;    lq = q-NT-2*NI-NH; }
    else if (q < NT+2*NI+2*NH+NH0){ src = h0; dst = hInit;           lq = q-NT-2*NI-2*NH; }
    else { lq = q-NT-2*NI-2*NH-NH0; src = Wout; dst = WoutP; zero = (lq >= cT*cE/4); }
    float4 v = make_float4(0.f,0.f,0.f,0.f);
    if (!zero) v = *(const float4*)(src + (size_t)lq * 4);
    ushort4 u;
    u.x = f2bf(v.x); u.y = f2bf(v.y); u.z = f2bf(v.z); u.w = f2bf(v.w);
    *(ushort4*)(dst + (size_t)lq * 4) = u;
  }
}

// ---------------------------------------------------------------------------
// Embed projection (unchanged R4/R5): bf16 MFMA + global_load_lds staging,
// XCD-aware 1D remap. P[m][n] = sum_k tbl[ids(m)][k]*Wih[n][k] + b1[n]+b2[n]
// ---------------------------------------------------------------------------
__global__ __launch_bounds__(256) void k_embed_mfma(
    const int* __restrict__ ids,
    const unsigned short* __restrict__ tbl,
    const unsigned short* __restrict__ Wih,
    const float* __restrict__ b1f, const float* __restrict__ b2f,
    const float* __restrict__ b1b, const float* __restrict__ b2b,
    __hip_bfloat16* __restrict__ Pf, __hip_bfloat16* __restrict__ Pb)
{
  const int bid = blockIdx.x;
  const int xcd = bid & 7;
  const int jj  = bid >> 3;
  const int m_tile = xcd * 32 + (jj >> 4);
  const int nz  = jj & 15;
  const int n_tile = nz & 7;
  const int d   = nz >> 3;

  const unsigned short* W = Wih + (size_t)d * cNG * cE;
  const float* b1 = d ? b1b : b1f;
  const float* b2 = d ? b2b : b2f;
  unsigned short* P = (unsigned short*)(d ? Pb : Pf);

  const int n0 = n_tile * 128;
  const int m0 = m_tile * 128;
  const int tid = threadIdx.x;

  __shared__ unsigned short Al[128 * 64];
  __shared__ unsigned short Bl[128 * 64];
  __shared__ float bias_s[128];
  if (tid < 128) bias_s[tid] = b1[n0 + tid] + b2[n0 + tid];

  const int lane = tid & 63, wave = tid >> 6;
  const int wm = wave >> 1, wn = wave & 1;
  const int fr = lane & 15, fq = lane >> 4;

  const int srow = wave * 32;
  const int lrow = lane >> 3;
  const int lch  = lane & 7;
  int aid[4];
#pragma unroll
  for (int q = 0; q < 4; ++q) {
    const int m = m0 + srow + q * 8 + lrow;
    aid[q] = ids[(m & (cB - 1)) * cS + (m >> 8)];
  }

  f32x4 acc[4][4];
#pragma unroll
  for (int i = 0; i < 4; ++i)
#pragma unroll
    for (int j = 0; j < 4; ++j) acc[i][j] = (f32x4){0.f, 0.f, 0.f, 0.f};

  for (int kt = 0; kt < cE / 64; ++kt) {
    __syncthreads();
#pragma unroll
    for (int q = 0; q < 4; ++q) {
      const unsigned short* ga = tbl + (size_t)aid[q] * cE + kt * 64 + lch * 8;
      const unsigned short* gb = W + (size_t)(n0 + srow + q * 8 + lrow) * cE + kt * 64 + lch * 8;
      gload_lds16(ga, Al + (srow + q * 8) * 64);
      gload_lds16(gb, Bl + (srow + q * 8) * 64);
    }
    __syncthreads();
#pragma unroll
    for (int ks = 0; ks < 2; ++ks) {
      bf16x8 aF[4], bF[4];
#pragma unroll
      for (int i = 0; i < 4; ++i)
        aF[i] = *(const bf16x8*)(Al + (wm * 64 + i * 16 + fr) * 64 + ks * 32 + fq * 8);
#pragma unroll
      for (int j = 0; j < 4; ++j)
        bF[j] = *(const bf16x8*)(Bl + (wn * 64 + j * 16 + fr) * 64 + ks * 32 + fq * 8);
#pragma unroll
      for (int i = 0; i < 4; ++i)
#pragma unroll
        for (int j = 0; j < 4; ++j)
          acc[i][j] = __builtin_amdgcn_mfma_f32_16x16x32_bf16(aF[i], bF[j], acc[i][j], 0, 0, 0);
    }
  }

#pragma unroll
  for (int i = 0; i < 4; ++i)
#pragma unroll
    for (int j = 0; j < 4; ++j) {
      const int gcol = wn * 64 + j * 16 + fr;
#pragma unroll
      for (int r = 0; r < 4; ++r) {
        const int grow = m0 + wm * 64 + i * 16 + fq * 4 + r;
        P[(size_t)grow * cNG + n0 + gcol] = f2bf(acc[i][j][r] + bias_s[gcol]);
      }
    }
}

// ---------------------------------------------------------------------------
// Persistent LSTM v5 (de-risked): 64 blocks x 256 thr (4 waves).
// Group = (dir, b-tile32) = 4 BLOCKS (16 waves). Only PROVEN mechanisms:
//   - h exchange: RELAXED AGENT-scope 8B atomic loads/stores (R5, 489us OK)
//   - barrier: monotone agent-scope counter, 4 participants (was 16)
//   - intra-block: __syncthreads (drains vmcnt -> h stores at coherence pt)
//   - P[t+1] prefetched BEFORE the barrier (retires under drain+poll)
// No inline asm, no XCD assumptions, no workgroup-scope global atomics.
// W_hh in 128 VGPRs/wave, c in regs. __launch_bounds__(256,1): full budget.
// ---------------------------------------------------------------------------
__global__ __launch_bounds__(256, 1) void k_lstm_grp(
    const unsigned short* __restrict__ Wbf,   // [2][1024][256] bf16
    const unsigned short* __restrict__ Pf_,
    const unsigned short* __restrict__ Pb_,
    const float* __restrict__ c0,             // [2][256][256] f32
    const unsigned short* __restrict__ hInit, // [2][256][256] bf16
    unsigned short* __restrict__ hHist,       // [S][2][256][256] bf16
    unsigned int* __restrict__ bar)
{
  const int bid = blockIdx.x;
  const int g   = bid >> 2;            // group 0..15
  const int mem = bid & 3;             // member 0..3
  const int d   = g >> 3;
  const int b0  = (g & 7) * 32;
  const int tid = threadIdx.x;
  const int lane = tid & 63, w = tid >> 6;
  const int fr = lane & 15, fq = lane >> 4;
  const int j0 = (mem * 4 + w) * 16;
  const int jj = j0 + fr;
  unsigned int* cnt = bar + g * 32;    // 128B-spaced counters

  __shared__ unsigned short hs[4][512];  // per-wave 32x16 h staging

  const unsigned short* P = d ? Pb_ : Pf_;
  const unsigned short* wbase = Wbf + (size_t)d * cNG * cHD;

  // ---- W_hh fragments resident in registers: wreg[k0][gate] ----
  bf16x8 wreg[8][4];
#pragma unroll
  for (int k0 = 0; k0 < 8; ++k0)
#pragma unroll
    for (int gg = 0; gg < 4; ++gg)
      wreg[k0][gg] = *(const bf16x8*)(wbase + (size_t)(gg * cHD + j0 + fr) * cHD + k0 * 32 + fq * 8);

  // ---- c resident in registers ----
  float creg[8];
#pragma unroll
  for (int mf = 0; mf < 2; ++mf)
#pragma unroll
    for (int r = 0; r < 4; ++r)
      creg[mf * 4 + r] = c0[d * cBH + (b0 + mf * 16 + fq * 4 + r) * cHD + jj];

  // ---- P prefetch for step 0 ----
  unsigned short pv[4][8], pvn[4][8];
  {
    const unsigned short* Pt = P + (size_t)(d ? cS - 1 : 0) * cB * cNG;
#pragma unroll
    for (int gg = 0; gg < 4; ++gg)
#pragma unroll
      for (int mf = 0; mf < 2; ++mf)
#pragma unroll
        for (int r = 0; r < 4; ++r)
          pv[gg][mf * 4 + r] = Pt[(size_t)(b0 + mf * 16 + fq * 4 + r) * cNG + gg * cHD + jj];
  }

  for (int t = 0; t < cS; ++t) {
    const int te = d ? (cS - 1 - t) : t;

    // ---- A-fragment loads (h_{t-1}): agent-scope 8B atomics (memory-side)
    const unsigned short* hsrc;
    if (t == 0) hsrc = hInit + (size_t)d * cBH;
    else {
      const int tp = d ? (te + 1) : (te - 1);
      hsrc = hHist + (((size_t)tp * 2 + d) * cBH);
    }
    bf16x8 areg[2][8];
#pragma unroll
    for (int mf = 0; mf < 2; ++mf)
#pragma unroll
      for (int k0 = 0; k0 < 8; ++k0) {
        const ull_t* ap = (const ull_t*)(hsrc + (size_t)(b0 + mf * 16 + fr) * cHD + k0 * 32 + fq * 8);
        union { ull_t u[2]; bf16x8 v; } tmp;
        tmp.u[0] = __hip_atomic_load((ull_t*)ap,       __ATOMIC_RELAXED, __HIP_MEMORY_SCOPE_AGENT);
        tmp.u[1] = __hip_atomic_load((ull_t*)(ap + 1), __ATOMIC_RELAXED, __HIP_MEMORY_SCOPE_AGENT);
        areg[mf][k0] = tmp.v;
      }

    // ---- MFMA: M=32, N=16 x 4 gates, K=256 ----
    f32x4 acc[2][4];
#pragma unroll
    for (int mf = 0; mf < 2; ++mf)
#pragma unroll
      for (int gg = 0; gg < 4; ++gg) acc[mf][gg] = (f32x4){0.f, 0.f, 0.f, 0.f};
#pragma unroll
    for (int k0 = 0; k0 < 8; ++k0)
#pragma unroll
      for (int gg = 0; gg < 4; ++gg) {
        acc[0][gg] = __builtin_amdgcn_mfma_f32_16x16x32_bf16(areg[0][k0], wreg[k0][gg], acc[0][gg], 0, 0, 0);
        acc[1][gg] = __builtin_amdgcn_mfma_f32_16x16x32_bf16(areg[1][k0], wreg[k0][gg], acc[1][gg], 0, 0, 0);
      }

    // ---- gates -> c,h ; h into per-wave LDS staging (transpose) ----
#pragma unroll
    for (int mf = 0; mf < 2; ++mf)
#pragma unroll
      for (int r = 0; r < 4; ++r) {
        const float zi = acc[mf][0][r] + bf2f(pv[0][mf * 4 + r]);
        const float zf = acc[mf][1][r] + bf2f(pv[1][mf * 4 + r]);
        const float zg = acc[mf][2][r] + bf2f(pv[2][mf * 4 + r]);
        const float zo = acc[mf][3][r] + bf2f(pv[3][mf * 4 + r]);
        const float cc = fsig(zf) * creg[mf * 4 + r] + fsig(zi) * ftanh_(zg);
        creg[mf * 4 + r] = cc;
        hs[w][(mf * 16 + fq * 4 + r) * 16 + fr] = f2bf(fsig(zo) * ftanh_(cc));
      }
    __syncthreads();   // hs visible (also orders LDS before the global stores)

    // ---- h slice to global: 2x8B agent-scope atomic stores per lane ----
    {
      const int row = lane >> 1, half = lane & 1;
      const size_t idx = (((size_t)te * 2 + d) * cBH) + (size_t)(b0 + row) * cHD + j0 + half * 8;
      __hip_atomic_store((ull_t*)(hHist + idx),     *(const ull_t*)(&hs[w][row * 16 + half * 8]),
                         __ATOMIC_RELAXED, __HIP_MEMORY_SCOPE_AGENT);
      __hip_atomic_store((ull_t*)(hHist + idx + 4), *(const ull_t*)(&hs[w][row * 16 + half * 8 + 4]),
                         __ATOMIC_RELAXED, __HIP_MEMORY_SCOPE_AGENT);
    }

    if (t != cS - 1) {
      // ---- prefetch P[t+1] now: retires during the drain + poll below ----
      const int tn = d ? (te - 1) : (te + 1);
      const unsigned short* Pt = P + (size_t)tn * cB * cNG;
#pragma unroll
      for (int gg = 0; gg < 4; ++gg)
#pragma unroll
        for (int mf = 0; mf < 2; ++mf)
#pragma unroll
          for (int r = 0; r < 4; ++r)
            pvn[gg][mf * 4 + r] = Pt[(size_t)(b0 + mf * 16 + fq * 4 + r) * cNG + gg * cHD + jj];

      // ---- group barrier: syncthreads drains all 4 waves' stores; then
      //      one monotone agent-scope counter among the 4 member blocks ----
      __syncthreads();
      if (tid == 0) {
        const unsigned int target = 4u * (unsigned int)(t + 1);
        __hip_atomic_fetch_add(cnt, 1u, __ATOMIC_RELAXED, __HIP_MEMORY_SCOPE_AGENT);
        while (__hip_atomic_load(cnt, __ATOMIC_RELAXED, __HIP_MEMORY_SCOPE_AGENT) < target)
          __builtin_amdgcn_s_sleep(0);
      }
      __syncthreads();

#pragma unroll
      for (int gg = 0; gg < 4; ++gg)
#pragma unroll
        for (int q = 0; q < 8; ++q) pv[gg][q] = pvn[gg][q];
    }
  }
}

// ---------------------------------------------------------------------------
// Emissions: bf16 MFMA. em[m][n] = sum_k hfeat[m][k]*WoutP[n][k] + b_out[n]
// ---------------------------------------------------------------------------
__global__ __launch_bounds__(256) void k_em_mfma(
    const unsigned short* __restrict__ hHist,  // [S][2][256][256] bf16
    const unsigned short* __restrict__ WoutP,  // [128][512] bf16 (rows>=76 = 0)
    const float* __restrict__ b_out, float* __restrict__ em)
{
  const int m0 = blockIdx.x * 128;
  const int tid = threadIdx.x;

  __shared__ unsigned short Al[128 * 64];
  __shared__ unsigned short Bl[128 * 64];
  __shared__ float bias_s[128];
  if (tid < 128) bias_s[tid] = (tid < cT) ? b_out[tid] : 0.f;

  const int lane = tid & 63, wave = tid >> 6;
  const int wm = wave >> 1, wn = wave & 1;
  const int fr = lane & 15, fq = lane >> 4;
  const int srow = wave * 32;
  const int lrow = lane >> 3;
  const int lch  = lane & 7;

  f32x4 acc[4][4];
#pragma unroll
  for (int i = 0; i < 4; ++i)
#pragma unroll
    for (int j = 0; j < 4; ++j) acc[i][j] = (f32x4){0.f, 0.f, 0.f, 0.f};

  for (int kt = 0; kt < 8; ++kt) {
    const int d  = kt >> 2;
    const int ko = (kt & 3) * 64;
    __syncthreads();
#pragma unroll
    for (int q = 0; q < 4; ++q) {
      const int row = srow + q * 8 + lrow;
      const int m = m0 + row;
      const int t = m >> 8, b = m & 255;
      const unsigned short* ga = hHist + (((size_t)t * 2 + d) * cB + b) * cHD + ko + lch * 8;
      const unsigned short* gb = WoutP + (size_t)row * cH + kt * 64 + lch * 8;
      gload_lds16(ga, Al + (srow + q * 8) * 64);
      gload_lds16(gb, Bl + (srow + q * 8) * 64);
    }
    __syncthreads();
#pragma unroll
    for (int ks = 0; ks < 2; ++ks) {
      bf16x8 aF[4], bF[4];
#pragma unroll
      for (int i = 0; i < 4; ++i)
        aF[i] = *(const bf16x8*)(Al + (wm * 64 + i * 16 + fr) * 64 + ks * 32 + fq * 8);
#pragma unroll
      for (int j = 0; j < 4; ++j)
        bF[j] = *(const bf16x8*)(Bl + (wn * 64 + j * 16 + fr) * 64 + ks * 32 + fq * 8);
#pragma unroll
      for (int i = 0; i < 4; ++i)
#pragma unroll
        for (int j = 0; j < 4; ++j)
          acc[i][j] = __builtin_amdgcn_mfma_f32_16x16x32_bf16(aF[i], bF[j], acc[i][j], 0, 0, 0);
    }
  }

#pragma unroll
  for (int i = 0; i < 4; ++i)
#pragma unroll
    for (int j = 0; j < 4; ++j) {
      const int gcol = wn * 64 + j * 16 + fr;
      if (gcol < cT) {
#pragma unroll
        for (int r = 0; r < 4; ++r) {
          const int grow = m0 + wm * 64 + i * 16 + fq * 4 + r;
          em[(size_t)grow * cT + gcol] = acc[i][j][r] + bias_s[gcol];
        }
      }
    }
}

// ---------------------------------------------------------------------------
// CRF: one block per batch element, 320 threads (5 waves). (unchanged R2)
// ---------------------------------------------------------------------------
__global__ __launch_bounds__(320) void k_crf(
    const float* __restrict__ em,
    const int* __restrict__ tag_ids,
    const int* __restrict__ lengths,
    const float* __restrict__ start_trans,
    const float* __restrict__ end_trans,
    const float* __restrict__ trans,
    float* __restrict__ llh)
{
  const int b = blockIdx.x;
  const int tid = threadIdx.x;
  const int len = lengths[b];

  __shared__ float trans_t[80 * 81];
  __shared__ float em_s[cS * 80];
  __shared__ float a0[80], a1[80];
  __shared__ float red[128];
  __shared__ float score_sh;

  for (int idx = tid; idx < cT * cT; idx += 320) {
    const int i = idx / cT, jt = idx - i * cT;
    trans_t[jt * 81 + i] = trans[idx];
  }
  for (int idx = tid; idx < cS * cT; idx += 320) {
    const int t = idx / cT, jt = idx - t * cT;
    em_s[t * 80 + jt] = em[((size_t)t * cB + b) * cT + jt];
  }
  __syncthreads();

  float contrib = 0.f;
  if (tid < cS) {
    const int t = tid;
    if (t == 0) {
      const int tg = tag_ids[b * cS];
      contrib = start_trans[tg] + em_s[tg];
    } else if (t < len) {
      const int tg = tag_ids[b * cS + t];
      const int tp = tag_ids[b * cS + t - 1];
      contrib = trans_t[tg * 81 + tp] + em_s[t * 80 + tg];
    }
    if (t == len - 1) contrib += end_trans[tag_ids[b * cS + len - 1]];
  }
  if (tid < 128) red[tid] = contrib;
  __syncthreads();
  for (int s = 64; s > 0; s >>= 1) {
    if (tid < s) red[tid] += red[tid + s];
    __syncthreads();
  }
  if (tid == 0) score_sh = red[0];

  const int j   = tid >> 2;
  const int sub = tid & 3;
  const int i0  = sub * 19;
  float* cur = a0;
  float* nxt = a1;
  if (sub == 0 && j < cT) cur[j] = start_trans[j] + em_s[j];
  __syncthreads();
  for (int t = 1; t < len; ++t) {
    const float mref = cur[0];
    const float* trow = &trans_t[j * 81 + i0];
    const float* crow = &cur[i0];
    float s = 0.f;
#pragma unroll
    for (int q = 0; q < 19; ++q)
      s += __expf(crow[q] + trow[q] - mref);
    s += __shfl_xor(s, 1);
    s += __shfl_xor(s, 2);
    if (sub == 0 && j < cT) nxt[j] = mref + __logf(s) + em_s[t * 80 + j];
    __syncthreads();
    float* tp2 = cur; cur = nxt; nxt = tp2;
  }

  const float v = (tid < cT) ? cur[tid] + end_trans[tid] : -1e30f;
  if (tid < 128) red[tid] = v;
  __syncthreads();
  for (int s = 64; s > 0; s >>= 1) {
    if (tid < s) red[tid] = fmaxf(red[tid], red[tid + s]);
    __syncthreads();
  }
  const float mx = red[0];
  __syncthreads();
  if (tid < 128) red[tid] = (tid < cT) ? __expf(v - mx) : 0.f;
  __syncthreads();
  for (int s = 64; s > 0; s >>= 1) {
    if (tid < s) red[tid] += red[tid + s];
    __syncthreads();
  }
  if (tid == 0) llh[b] = score_sh - (mx + __logf(red[0]));
}

__global__ __launch_bounds__(256) void k_final(const float* __restrict__ llh,
                                               float* __restrict__ out)
{
  __shared__ float red[256];
  const int tid = threadIdx.x;
  red[tid] = llh[tid];
  __syncthreads();
  for (int s = 128; s > 0; s >>= 1) {
    if (tid < s) red[tid] += red[tid + s];
    __syncthreads();
  }
  if (tid == 0) out[0] = -red[0] * (1.0f / cB);
}

} // anonymous namespace

extern "C" void kernel_launch(void* const* d_in, const int* in_sizes, int n_in,
                              void* d_out, int out_size, void* d_ws, size_t ws_size,
                              hipStream_t stream) {
  const int*   input_ids   = (const int*)  d_in[0];
  const int*   tag_ids     = (const int*)  d_in[1];
  const int*   lengths     = (const int*)  d_in[2];
  const float* embed_table = (const float*)d_in[3];
  const float* W_ih_f      = (const float*)d_in[4];
  const float* W_hh_f      = (const float*)d_in[5];
  const float* b_ih_f      = (const float*)d_in[6];
  const float* b_hh_f      = (const float*)d_in[7];
  const float* W_ih_b      = (const float*)d_in[8];
  const float* W_hh_b      = (const float*)d_in[9];
  const float* b_ih_b      = (const float*)d_in[10];
  const float* b_hh_b      = (const float*)d_in[11];
  const float* W_out       = (const float*)d_in[12];
  const float* b_out       = (const float*)d_in[13];
  const float* start_trans = (const float*)d_in[14];
  const float* end_trans   = (const float*)d_in[15];
  const float* trans       = (const float*)d_in[16];
  const float* h0          = (const float*)d_in[17];
  const float* c0          = (const float*)d_in[18];
  float* out = (float*)d_out;

  // workspace layout (lifetime-aliased; ~180 MiB total):
  //  [0,64M) Pf   [64M,128M) Pb
  //  [128M,+30.72M) tbl (embed-only) / hHist [128M,+32M) (lstm+em; tbl dead)
  //  [160M,+4M) wih (embed-only)
  //  [165M,+9.96M) em f32 (post-lstm)
  //  [176M...) whh, hInit, WoutP, llh, bar
  char* wsb = (char*)d_ws;
  const size_t MB = 1024 * 1024;
  __hip_bfloat16* Pf = (__hip_bfloat16*)(wsb);
  __hip_bfloat16* Pb = (__hip_bfloat16*)(wsb + 64 * MB);
  unsigned short* tbl   = (unsigned short*)(wsb + 128 * MB);
  unsigned short* hHist = (unsigned short*)(wsb + 128 * MB);   // aliases tbl
  unsigned short* wih   = (unsigned short*)(wsb + 160 * MB);
  float*          em    = (float*)         (wsb + 165 * MB);
  unsigned short* whh   = (unsigned short*)(wsb + 176 * MB);   // 1 MiB
  unsigned short* hInit = (unsigned short*)(wsb + 177 * MB);   // 256 KiB
  unsigned short* WoutP = (unsigned short*)(wsb + 178 * MB);   // 128 KiB
  float*          llh   = (float*)         (wsb + 179 * MB);
  unsigned int*   bar   = (unsigned int*)  (wsb + 179 * MB + 4096);

  // 0) prep: bf16 conversions + padded W_out + barrier zeroing
  k_prep<<<4096, 256, 0, stream>>>(embed_table, W_ih_f, W_ih_b, W_hh_f, W_hh_b,
                                   h0, W_out, tbl, wih, whh, hInit, WoutP, bar);

  // 1) input projections (gather GEMM), bf16 MFMA + global_load_lds staging
  k_embed_mfma<<<4096, 256, 0, stream>>>(input_ids, tbl, wih,
                                         b_ih_f, b_hh_f, b_ih_b, b_hh_b, Pf, Pb);

  // 2) full recurrence: persistent, 4-member groups, agent-scope exchange
  k_lstm_grp<<<64, 256, 0, stream>>>(whh, (const unsigned short*)Pf,
                                     (const unsigned short*)Pb,
                                     c0, hInit, hHist, bar);

  // 3) emissions from bf16 h-history (MFMA)
  k_em_mfma<<<cM / 128, 256, 0, stream>>>(hHist, WoutP, b_out, em);

  // 4) CRF per batch element + final mean
  k_crf<<<cB, 320, 0, stream>>>(em, tag_ids, lengths, start_trans, end_trans, trans, llh);
  k_final<<<1, 256, 0, stream>>>(llh, out);
}